// Round 1
// baseline (612.467 us; speedup 1.0000x reference)
//
#include <hip/hip_runtime.h>

#define NTOK   8192
#define DMODEL 1024
#define NC     64
#define NK     16
#define NP     64
#define NM     128
#define LCAP   (1 << 20)
#define MARGIN 0.05f

// ------------------------------------------------------------------
// Kernel 1: fp32 GEMM (proj = x @ W^T) fused with d2 + argmin + gap.
// Grid: (64 token-blocks, 16 out-tiles). Tile = 128 tokens x 128 outs.
// Out-tile -> set = ot>>3, codebooks cbase..cbase+7 (8 cb x 16 k).
// Epilogue: per 64-token half, per 4-codebook half: stage emb in LDS,
// compute g[p] = e2[p] - 2*proj.emb[p], argmin with first-index ties,
// record top-2 gap; gap < MARGIN -> append (set,c,tok) to refine list.
// ------------------------------------------------------------------
__global__ __launch_bounds__(256, 2) void k_proj_argmin(
    const float* __restrict__ x,
    const float* __restrict__ W_A, const float* __restrict__ W_B,
    const float* __restrict__ emb_A, const float* __restrict__ emb_B,
    int* __restrict__ idxbuf, int* __restrict__ list, int* __restrict__ cnt)
{
    __shared__ float smem[12608];          // 50.4 KB
    float* xs   = smem;                    // staging x^T: [32][132]
    float* ws   = smem + 4224;             // staging w^T: [32][132]
    float* proj = smem;                    // epilogue: [64][129]
    float* embS = smem + 8256;             // [4][64][16]
    float* e2S  = smem + 12352;            // [4*64]

    const int tid = threadIdx.x;
    const int tb  = blockIdx.x;            // token block 0..63
    const int ot  = blockIdx.y;            // out tile 0..15
    const int set = ot >> 3;
    const float* __restrict__ Wp = set ? W_B : W_A;
    const float* __restrict__ Ep = set ? emb_B : emb_A;
    const int cbase = (ot & 7) * 8;

    const int tr = tid >> 4;               // token group 0..15
    const int tc = tid & 15;               // out group 0..15

    float acc[8][8];
    #pragma unroll
    for (int i = 0; i < 8; ++i)
        #pragma unroll
        for (int j = 0; j < 8; ++j) acc[i][j] = 0.f;

    for (int k0 = 0; k0 < DMODEL; k0 += 32) {
        #pragma unroll
        for (int i = 0; i < 4; ++i) {
            const int s = tid + 256 * i;
            const int row = s >> 3, c4 = s & 7;
            const float4 vx = *(const float4*)(x + (size_t)(tb * 128 + row) * DMODEL + k0 + c4 * 4);
            xs[(c4 * 4 + 0) * 132 + row] = vx.x;
            xs[(c4 * 4 + 1) * 132 + row] = vx.y;
            xs[(c4 * 4 + 2) * 132 + row] = vx.z;
            xs[(c4 * 4 + 3) * 132 + row] = vx.w;
            const float4 vw = *(const float4*)(Wp + (size_t)(cbase * 16 + row) * DMODEL + k0 + c4 * 4);
            ws[(c4 * 4 + 0) * 132 + row] = vw.x;
            ws[(c4 * 4 + 1) * 132 + row] = vw.y;
            ws[(c4 * 4 + 2) * 132 + row] = vw.z;
            ws[(c4 * 4 + 3) * 132 + row] = vw.w;
        }
        __syncthreads();
        #pragma unroll 8
        for (int kk = 0; kk < 32; ++kk) {
            const float4 a0 = *(const float4*)&xs[kk * 132 + tr * 8];
            const float4 a1 = *(const float4*)&xs[kk * 132 + tr * 8 + 4];
            const float4 b0 = *(const float4*)&ws[kk * 132 + tc * 4];
            const float4 b1 = *(const float4*)&ws[kk * 132 + 64 + tc * 4];
            const float a[8] = {a0.x, a0.y, a0.z, a0.w, a1.x, a1.y, a1.z, a1.w};
            const float b[8] = {b0.x, b0.y, b0.z, b0.w, b1.x, b1.y, b1.z, b1.w};
            #pragma unroll
            for (int i = 0; i < 8; ++i)
                #pragma unroll
                for (int j = 0; j < 8; ++j)
                    acc[i][j] = fmaf(a[i], b[j], acc[i][j]);
        }
        __syncthreads();
    }

    // ---- epilogue: d2 + argmin, two token halves x two codebook halves ----
    for (int h = 0; h < 2; ++h) {
        __syncthreads();
        if ((tr >> 3) == h) {
            const int ltb = (tr & 7) * 8;
            #pragma unroll
            for (int i = 0; i < 8; ++i)
                #pragma unroll
                for (int j = 0; j < 4; ++j) {
                    proj[(ltb + i) * 129 + tc * 4 + j]      = acc[i][j];
                    proj[(ltb + i) * 129 + 64 + tc * 4 + j] = acc[i][4 + j];
                }
        }
        for (int ch = 0; ch < 2; ++ch) {
            __syncthreads();
            {   // stage 4 codebooks of emb (contiguous copy)
                const float4* eg = (const float4*)(Ep + (size_t)(cbase + ch * 4) * NP * NK);
                float4* es = (float4*)embS;
                #pragma unroll
                for (int i = 0; i < 4; ++i) es[tid + 256 * i] = eg[tid + 256 * i];
            }
            __syncthreads();
            {   // e2 per (c_local, p)
                const float* e = embS + tid * 16;
                float s = 0.f;
                #pragma unroll
                for (int k = 0; k < 16; ++k) s = fmaf(e[k], e[k], s);
                e2S[tid] = s;
            }
            __syncthreads();
            {
                const int cl = tid >> 6, lt = tid & 63;
                float pr[16];
                const float* pp = proj + lt * 129 + (ch * 4 + cl) * 16;
                #pragma unroll
                for (int k = 0; k < 16; ++k) pr[k] = pp[k];
                const float* eb = embS + cl * 1024;
                const float* e2 = e2S + cl * 64;
                float best = 1e30f, second = 1e30f;
                int bp = 0;
                for (int p = 0; p < 64; ++p) {
                    const float* e = eb + p * 16;
                    float s = 0.f;
                    #pragma unroll
                    for (int k = 0; k < 16; ++k) s = fmaf(pr[k], e[k], s);
                    const float g = fmaf(-2.f, s, e2[p]);
                    if (g < best) { second = best; best = g; bp = p; }
                    else if (g < second) { second = g; }
                }
                const int c = cbase + ch * 4 + cl;
                const int gtok = tb * 128 + h * 64 + lt;
                idxbuf[(set * NC + c) * NTOK + gtok] = bp;
                if (second - best < MARGIN) {
                    const int slot = atomicAdd(cnt, 1);
                    if (slot < LCAP) list[slot] = (set << 19) | (c << 13) | gtok;
                }
            }
        }
    }
}

// ------------------------------------------------------------------
// Kernel 2: fp64 exact re-resolution of flagged near-tie argmins.
// One wave per case: cooperative K x D projection, full P=64 distance
// argmin in fp64, first-index tie-break.
// ------------------------------------------------------------------
__global__ __launch_bounds__(256) void k_refine(
    const float* __restrict__ x,
    const float* __restrict__ W_A, const float* __restrict__ W_B,
    const float* __restrict__ emb_A, const float* __restrict__ emb_B,
    const int* __restrict__ list, const int* __restrict__ cnt,
    int* __restrict__ idxbuf)
{
    int n = *cnt;
    if (n > LCAP) n = LCAP;
    const int lane = threadIdx.x & 63;
    const int wave = (int)((blockIdx.x * blockDim.x + threadIdx.x) >> 6);
    const int nw   = (int)((gridDim.x * blockDim.x) >> 6);

    for (int i = wave; i < n; i += nw) {
        const int code = list[i];
        const int tok = code & 8191;
        const int c   = (code >> 13) & 63;
        const int set = (code >> 19) & 1;
        const float* __restrict__ Wp = set ? W_B : W_A;
        const float* __restrict__ Ep = set ? emb_B : emb_A;

        double pk[16];
        #pragma unroll
        for (int k = 0; k < 16; ++k) pk[k] = 0.0;
        for (int dd = 0; dd < 16; ++dd) {
            const int d = dd * 64 + lane;
            const double xv = (double)x[(size_t)tok * DMODEL + d];
            #pragma unroll
            for (int k = 0; k < 16; ++k)
                pk[k] = fma(xv, (double)Wp[(size_t)(c * 16 + k) * DMODEL + d], pk[k]);
        }
        #pragma unroll
        for (int k = 0; k < 16; ++k) {
            #pragma unroll
            for (int off = 32; off; off >>= 1)
                pk[k] += __shfl_xor(pk[k], off, 64);
        }
        // lane p = lane: exact squared distance
        double d2 = 0.0;
        #pragma unroll
        for (int k = 0; k < 16; ++k) {
            const double t = pk[k] - (double)Ep[(size_t)(c * NP + lane) * NK + k];
            d2 = fma(t, t, d2);
        }
        int bp = lane;
        double bv = d2;
        #pragma unroll
        for (int off = 32; off; off >>= 1) {
            const double ov = __shfl_xor(bv, off, 64);
            const int    op = __shfl_xor(bp, off, 64);
            if (ov < bv || (ov == bv && op < bp)) { bv = ov; bp = op; }
        }
        if (lane == 0) idxbuf[(set * NC + c) * NTOK + tok] = bp;
    }
}

// ------------------------------------------------------------------
// Kernel 3: per-token gather + t[r] + out[d]. One block per token.
// t[r] = sum_{c in 8r..8r+7} sum_m x[(c&7)*128+m] * vals_A[c, idxA[c], m]
// out[d] = sum_r t[r] * vals_B[8r + d/128, idxB[.], d%128]
// ------------------------------------------------------------------
__global__ __launch_bounds__(256) void k_combine(
    const float* __restrict__ x,
    const float* __restrict__ vals_A, const float* __restrict__ vals_B,
    const int* __restrict__ idxbuf, float* __restrict__ out)
{
    __shared__ float xsh[1032];   // x row, +1 pad per 128
    __shared__ float part[256];
    __shared__ float tsh[8];
    __shared__ int sIA[64];
    __shared__ int sIB[64];

    const int tid = threadIdx.x;
    const int tok = blockIdx.x;

    if (tid < 64) {
        sIA[tid] = idxbuf[tid * NTOK + tok];
        sIB[tid] = idxbuf[(NC + tid) * NTOK + tok];
    }
    {
        const float4 v = *(const float4*)(x + (size_t)tok * DMODEL + tid * 4);
        const int base = tid * 4 + (tid >> 5);
        xsh[base + 0] = v.x;
        xsh[base + 1] = v.y;
        xsh[base + 2] = v.z;
        xsh[base + 3] = v.w;
    }
    __syncthreads();
    {
        const int c = tid & 63, mseg = tid >> 6;
        const int ia = sIA[c];
        const float4* va = (const float4*)(vals_A + (size_t)(c * NP + ia) * NM + mseg * 32);
        const float* xb = xsh + (c & 7) * 129 + mseg * 32;
        float s = 0.f;
        #pragma unroll
        for (int i = 0; i < 8; ++i) {
            const float4 v = va[i];
            s = fmaf(v.x, xb[i * 4 + 0], s);
            s = fmaf(v.y, xb[i * 4 + 1], s);
            s = fmaf(v.z, xb[i * 4 + 2], s);
            s = fmaf(v.w, xb[i * 4 + 3], s);
        }
        part[tid] = s;
    }
    __syncthreads();
    if (tid < 8) {
        float s = 0.f;
        #pragma unroll
        for (int m = 0; m < 4; ++m)
            #pragma unroll
            for (int j = 0; j < 8; ++j)
                s += part[m * 64 + tid * 8 + j];
        tsh[tid] = s;
    }
    __syncthreads();
    {
        const int d0 = tid * 4, dblk = tid >> 5, dm = d0 & 127;
        float o0 = 0.f, o1 = 0.f, o2 = 0.f, o3 = 0.f;
        #pragma unroll
        for (int r = 0; r < 8; ++r) {
            const int cb = 8 * r + dblk;
            const int ib = sIB[cb];
            const float4 v = *(const float4*)(vals_B + (size_t)(cb * NP + ib) * NM + dm);
            const float tv = tsh[r];
            o0 = fmaf(tv, v.x, o0);
            o1 = fmaf(tv, v.y, o1);
            o2 = fmaf(tv, v.z, o2);
            o3 = fmaf(tv, v.w, o3);
        }
        *(float4*)(out + (size_t)tok * DMODEL + d0) = make_float4(o0, o1, o2, o3);
    }
}

extern "C" void kernel_launch(void* const* d_in, const int* in_sizes, int n_in,
                              void* d_out, int out_size, void* d_ws, size_t ws_size,
                              hipStream_t stream)
{
    const float* x      = (const float*)d_in[0];
    const float* W_A    = (const float*)d_in[1];
    const float* emb_A  = (const float*)d_in[2];
    const float* vals_A = (const float*)d_in[3];
    const float* W_B    = (const float*)d_in[4];
    const float* emb_B  = (const float*)d_in[5];
    const float* vals_B = (const float*)d_in[6];
    float* out = (float*)d_out;

    // ws layout: [0..16) count, [16 .. 16+4*LCAP) list, then idxbuf (2*64*8192 ints)
    int* cnt    = (int*)d_ws;
    int* list   = (int*)((char*)d_ws + 16);
    int* idxbuf = (int*)((char*)d_ws + 16 + sizeof(int) * (size_t)LCAP);

    hipMemsetAsync(cnt, 0, sizeof(int), stream);
    k_proj_argmin<<<dim3(64, 16), 256, 0, stream>>>(x, W_A, W_B, emb_A, emb_B, idxbuf, list, cnt);
    k_refine<<<1024, 256, 0, stream>>>(x, W_A, W_B, emb_A, emb_B, list, cnt, idxbuf);
    k_combine<<<NTOK, 256, 0, stream>>>(x, vals_A, vals_B, idxbuf, out);
}

// Round 2
// 250.559 us; speedup vs baseline: 2.4444x; 2.4444x over previous
//
#include <hip/hip_runtime.h>

#define NTOK   8192
#define DMODEL 1024
#define NC     64
#define NK     16
#define NP     64
#define NM     128
#define LCAP   (1 << 18)
#define MARGIN 0.01f

typedef short bf16x8 __attribute__((ext_vector_type(8)));
typedef float f32x4  __attribute__((ext_vector_type(4)));

#define AS1 __attribute__((address_space(1)))
#define AS3 __attribute__((address_space(3)))

__device__ __forceinline__ void glds16(const void* g, void* l) {
    __builtin_amdgcn_global_load_lds((const AS1 void*)g, (AS3 void*)l, 16, 0, 0);
}

__device__ __forceinline__ unsigned f2bf(float f) {
    unsigned u = __builtin_bit_cast(unsigned, f);
    return (u + 0x7FFFu + ((u >> 16) & 1u)) >> 16;
}
__device__ __forceinline__ float bf2f(unsigned s) {
    return __builtin_bit_cast(float, s << 16);
}

// ------------------------------------------------------------------
// Kernel 0: split x, W_A, W_B into bf16 hi/lo with subtiled layout
// [k/8][row][8] so the GEMM can stage via linear global_load_lds.
// unit u: x -> chunk = u>>13, tok = u&8191 ; W -> chunk = u>>10, ck = u&1023
// ------------------------------------------------------------------
__global__ __launch_bounds__(256) void k_split(
    const float* __restrict__ x, const float* __restrict__ W_A, const float* __restrict__ W_B,
    short* __restrict__ xh, short* __restrict__ xl,
    short* __restrict__ whA, short* __restrict__ wlA,
    short* __restrict__ whB, short* __restrict__ wlB)
{
    const int t = blockIdx.x * 256 + threadIdx.x;
    const int NX = 128 * NTOK;            // 1048576
    const int NW = 128 * 1024;            // 131072

    const float* src;
    short *dh, *dl;
    if (t < NX) {
        const int chunk = t >> 13, tok = t & 8191;
        src = x + (size_t)tok * DMODEL + chunk * 8;
        dh = xh + (size_t)t * 8; dl = xl + (size_t)t * 8;
    } else if (t < NX + NW) {
        const int u = t - NX, chunk = u >> 10, ck = u & 1023;
        src = W_A + (size_t)ck * DMODEL + chunk * 8;
        dh = whA + (size_t)u * 8; dl = wlA + (size_t)u * 8;
    } else {
        const int u = t - NX - NW, chunk = u >> 10, ck = u & 1023;
        src = W_B + (size_t)ck * DMODEL + chunk * 8;
        dh = whB + (size_t)u * 8; dl = wlB + (size_t)u * 8;
    }

    const float4 a = *(const float4*)src;
    const float4 b = *(const float4*)(src + 4);
    const float v[8] = {a.x, a.y, a.z, a.w, b.x, b.y, b.z, b.w};
    unsigned h[8], l[8];
    #pragma unroll
    for (int j = 0; j < 8; ++j) {
        h[j] = f2bf(v[j]);
        l[j] = f2bf(v[j] - bf2f(h[j]));
    }
    *(int4*)dh = make_int4((int)(h[0] | (h[1] << 16)), (int)(h[2] | (h[3] << 16)),
                           (int)(h[4] | (h[5] << 16)), (int)(h[6] | (h[7] << 16)));
    *(int4*)dl = make_int4((int)(l[0] | (l[1] << 16)), (int)(l[2] | (l[3] << 16)),
                           (int)(l[4] | (l[5] << 16)), (int)(l[6] | (l[7] << 16)));
}

// ------------------------------------------------------------------
// Kernel 1: bf16x3 MFMA GEMM (proj = x @ W^T) fused with d2 + argmin.
// Tile 128 tok x 128 ck, BK=64, 4 waves (2 tok x 2 ck), 16x16x32 MFMA.
// LDS tiles subtiled [chunk8][row128][16B] -> conflict-free ds_read_b128.
// Epilogue identical to the verified round-1 argmin (MARGIN-gap flags).
// ------------------------------------------------------------------
__global__ __launch_bounds__(256, 2) void k_mfma_argmin(
    const short* __restrict__ xh, const short* __restrict__ xl,
    const short* __restrict__ whA, const short* __restrict__ wlA,
    const short* __restrict__ whB, const short* __restrict__ wlB,
    const float* __restrict__ emb_A, const float* __restrict__ emb_B,
    int* __restrict__ idxbuf, int* __restrict__ list, int* __restrict__ cnt)
{
    __shared__ __align__(16) float smem[16384];   // 64 KB
    short* ls = (short*)smem;
    // GEMM: Ah units [0,1024), Al [1024,2048), Bh [2048,3072), Bl [3072,4096)
    float* proj = smem;                    // epilogue: [64][129]
    float* embS = smem + 8256;             // [4][64][16]
    float* e2S  = smem + 12352;            // [256]

    const int tid = threadIdx.x;
    const int tb  = blockIdx.x;            // token block 0..63
    const int ot  = blockIdx.y;            // out tile 0..15
    const int set = ot >> 3;
    const short* __restrict__ wh = set ? whB : whA;
    const short* __restrict__ wl = set ? wlB : wlA;
    const float* __restrict__ Ep = set ? emb_B : emb_A;
    const int cbase = (ot & 7) * 8;

    const int lane = tid & 63;
    const int wid  = tid >> 6;
    const int wr   = wid >> 1;             // token half 0..1
    const int wc   = wid & 1;              // ck half 0..1
    const int lrow = lane & 15;
    const int lk   = lane >> 4;

    f32x4 acc[4][4];
    #pragma unroll
    for (int m = 0; m < 4; ++m)
        #pragma unroll
        for (int n = 0; n < 4; ++n) acc[m][n] = (f32x4){0.f, 0.f, 0.f, 0.f};

    for (int k0c = 0; k0c < 128; k0c += 8) {   // 16 K-steps of BK=64
        #pragma unroll
        for (int i = 0; i < 4; ++i) {
            const int u = i * 256 + tid;        // 0..1023
            const int ch = u >> 7, r = u & 127;
            const size_t ga = ((size_t)(k0c + ch) * NTOK + tb * 128 + r) * 8;
            glds16(xh + ga, ls + (size_t)u * 8);
            glds16(xl + ga, ls + (size_t)(1024 + u) * 8);
            const size_t gb = ((size_t)(k0c + ch) * 1024 + cbase * 16 + r) * 8;
            glds16(wh + gb, ls + (size_t)(2048 + u) * 8);
            glds16(wl + gb, ls + (size_t)(3072 + u) * 8);
        }
        __syncthreads();
        #pragma unroll
        for (int ks = 0; ks < 2; ++ks) {
            const int cofs = ks * 4 + lk;
            bf16x8 ah[4], al[4], bh[4], bl[4];
            #pragma unroll
            for (int m = 0; m < 4; ++m) {
                const int ua = cofs * 128 + wr * 64 + m * 16 + lrow;
                ah[m] = *(const bf16x8*)(ls + (size_t)ua * 8);
                al[m] = *(const bf16x8*)(ls + (size_t)(1024 + ua) * 8);
                const int ub = cofs * 128 + wc * 64 + m * 16 + lrow;
                bh[m] = *(const bf16x8*)(ls + (size_t)(2048 + ub) * 8);
                bl[m] = *(const bf16x8*)(ls + (size_t)(3072 + ub) * 8);
            }
            #pragma unroll
            for (int m = 0; m < 4; ++m)
                #pragma unroll
                for (int n = 0; n < 4; ++n) {
                    acc[m][n] = __builtin_amdgcn_mfma_f32_16x16x32_bf16(ah[m], bh[n], acc[m][n], 0, 0, 0);
                    acc[m][n] = __builtin_amdgcn_mfma_f32_16x16x32_bf16(ah[m], bl[n], acc[m][n], 0, 0, 0);
                    acc[m][n] = __builtin_amdgcn_mfma_f32_16x16x32_bf16(al[m], bh[n], acc[m][n], 0, 0, 0);
                }
        }
        __syncthreads();
    }

    // ---- epilogue: d2 + argmin, two token halves x two codebook halves ----
    for (int h = 0; h < 2; ++h) {
        __syncthreads();
        if (wr == h) {
            #pragma unroll
            for (int m = 0; m < 4; ++m)
                #pragma unroll
                for (int n = 0; n < 4; ++n)
                    #pragma unroll
                    for (int r = 0; r < 4; ++r)
                        proj[(m * 16 + lk * 4 + r) * 129 + wc * 64 + n * 16 + lrow] = acc[m][n][r];
        }
        for (int ch = 0; ch < 2; ++ch) {
            __syncthreads();
            {   // stage 4 codebooks of emb (contiguous copy)
                const float4* eg = (const float4*)(Ep + (size_t)(cbase + ch * 4) * NP * NK);
                float4* es = (float4*)embS;
                #pragma unroll
                for (int i = 0; i < 4; ++i) es[tid + 256 * i] = eg[tid + 256 * i];
            }
            __syncthreads();
            {   // e2 per (c_local, p)
                const float* e = embS + tid * 16;
                float s = 0.f;
                #pragma unroll
                for (int k = 0; k < 16; ++k) s = fmaf(e[k], e[k], s);
                e2S[tid] = s;
            }
            __syncthreads();
            {
                const int cl = tid >> 6, lt = tid & 63;
                float pr[16];
                const float* pp = proj + lt * 129 + (ch * 4 + cl) * 16;
                #pragma unroll
                for (int k = 0; k < 16; ++k) pr[k] = pp[k];
                const float* eb = embS + cl * 1024;
                const float* e2 = e2S + cl * 64;
                float best = 1e30f, second = 1e30f;
                int bp = 0;
                for (int p = 0; p < 64; ++p) {
                    const float* e = eb + p * 16;
                    float s = 0.f;
                    #pragma unroll
                    for (int k = 0; k < 16; ++k) s = fmaf(pr[k], e[k], s);
                    const float g = fmaf(-2.f, s, e2[p]);
                    if (g < best) { second = best; best = g; bp = p; }
                    else if (g < second) { second = g; }
                }
                const int c = cbase + ch * 4 + cl;
                const int gtok = tb * 128 + h * 64 + lt;
                idxbuf[(set * NC + c) * NTOK + gtok] = bp;
                if (second - best < MARGIN) {
                    const int slot = atomicAdd(cnt, 1);
                    if (slot < LCAP) list[slot] = (set << 19) | (c << 13) | gtok;
                }
            }
        }
    }
}

// ------------------------------------------------------------------
// Kernel 2: fp64 exact re-resolution of flagged near-tie argmins.
// ------------------------------------------------------------------
__global__ __launch_bounds__(256) void k_refine(
    const float* __restrict__ x,
    const float* __restrict__ W_A, const float* __restrict__ W_B,
    const float* __restrict__ emb_A, const float* __restrict__ emb_B,
    const int* __restrict__ list, const int* __restrict__ cnt,
    int* __restrict__ idxbuf)
{
    int n = *cnt;
    if (n > LCAP) n = LCAP;
    const int lane = threadIdx.x & 63;
    const int wave = (int)((blockIdx.x * blockDim.x + threadIdx.x) >> 6);
    const int nw   = (int)((gridDim.x * blockDim.x) >> 6);

    for (int i = wave; i < n; i += nw) {
        const int code = list[i];
        const int tok = code & 8191;
        const int c   = (code >> 13) & 63;
        const int set = (code >> 19) & 1;
        const float* __restrict__ Wp = set ? W_B : W_A;
        const float* __restrict__ Ep = set ? emb_B : emb_A;

        double pk[16];
        #pragma unroll
        for (int k = 0; k < 16; ++k) pk[k] = 0.0;
        for (int dd = 0; dd < 16; ++dd) {
            const int d = dd * 64 + lane;
            const double xv = (double)x[(size_t)tok * DMODEL + d];
            #pragma unroll
            for (int k = 0; k < 16; ++k)
                pk[k] = fma(xv, (double)Wp[(size_t)(c * 16 + k) * DMODEL + d], pk[k]);
        }
        #pragma unroll
        for (int k = 0; k < 16; ++k) {
            #pragma unroll
            for (int off = 32; off; off >>= 1)
                pk[k] += __shfl_xor(pk[k], off, 64);
        }
        double d2 = 0.0;
        #pragma unroll
        for (int k = 0; k < 16; ++k) {
            const double t = pk[k] - (double)Ep[(size_t)(c * NP + lane) * NK + k];
            d2 = fma(t, t, d2);
        }
        int bp = lane;
        double bv = d2;
        #pragma unroll
        for (int off = 32; off; off >>= 1) {
            const double ov = __shfl_xor(bv, off, 64);
            const int    op = __shfl_xor(bp, off, 64);
            if (ov < bv || (ov == bv && op < bp)) { bv = ov; bp = op; }
        }
        if (lane == 0) idxbuf[(set * NC + c) * NTOK + tok] = bp;
    }
}

// ------------------------------------------------------------------
// Kernel 3: per-token gather + t[r] + out[d]. One block per token.
// ------------------------------------------------------------------
__global__ __launch_bounds__(256) void k_combine(
    const float* __restrict__ x,
    const float* __restrict__ vals_A, const float* __restrict__ vals_B,
    const int* __restrict__ idxbuf, float* __restrict__ out)
{
    __shared__ float xsh[1032];
    __shared__ float part[256];
    __shared__ float tsh[8];
    __shared__ int sIA[64];
    __shared__ int sIB[64];

    const int tid = threadIdx.x;
    const int tok = blockIdx.x;

    if (tid < 64) {
        sIA[tid] = idxbuf[tid * NTOK + tok];
        sIB[tid] = idxbuf[(NC + tid) * NTOK + tok];
    }
    {
        const float4 v = *(const float4*)(x + (size_t)tok * DMODEL + tid * 4);
        const int base = tid * 4 + (tid >> 5);
        xsh[base + 0] = v.x;
        xsh[base + 1] = v.y;
        xsh[base + 2] = v.z;
        xsh[base + 3] = v.w;
    }
    __syncthreads();
    {
        const int c = tid & 63, mseg = tid >> 6;
        const int ia = sIA[c];
        const float4* va = (const float4*)(vals_A + (size_t)(c * NP + ia) * NM + mseg * 32);
        const float* xb = xsh + (c & 7) * 129 + mseg * 32;
        float s = 0.f;
        #pragma unroll
        for (int i = 0; i < 8; ++i) {
            const float4 v = va[i];
            s = fmaf(v.x, xb[i * 4 + 0], s);
            s = fmaf(v.y, xb[i * 4 + 1], s);
            s = fmaf(v.z, xb[i * 4 + 2], s);
            s = fmaf(v.w, xb[i * 4 + 3], s);
        }
        part[tid] = s;
    }
    __syncthreads();
    if (tid < 8) {
        float s = 0.f;
        #pragma unroll
        for (int m = 0; m < 4; ++m)
            #pragma unroll
            for (int j = 0; j < 8; ++j)
                s += part[m * 64 + tid * 8 + j];
        tsh[tid] = s;
    }
    __syncthreads();
    {
        const int d0 = tid * 4, dblk = tid >> 5, dm = d0 & 127;
        float o0 = 0.f, o1 = 0.f, o2 = 0.f, o3 = 0.f;
        #pragma unroll
        for (int r = 0; r < 8; ++r) {
            const int cb = 8 * r + dblk;
            const int ib = sIB[cb];
            const float4 v = *(const float4*)(vals_B + (size_t)(cb * NP + ib) * NM + dm);
            const float tv = tsh[r];
            o0 = fmaf(tv, v.x, o0);
            o1 = fmaf(tv, v.y, o1);
            o2 = fmaf(tv, v.z, o2);
            o3 = fmaf(tv, v.w, o3);
        }
        *(float4*)(out + (size_t)tok * DMODEL + d0) = make_float4(o0, o1, o2, o3);
    }
}

extern "C" void kernel_launch(void* const* d_in, const int* in_sizes, int n_in,
                              void* d_out, int out_size, void* d_ws, size_t ws_size,
                              hipStream_t stream)
{
    const float* x      = (const float*)d_in[0];
    const float* W_A    = (const float*)d_in[1];
    const float* emb_A  = (const float*)d_in[2];
    const float* vals_A = (const float*)d_in[3];
    const float* W_B    = (const float*)d_in[4];
    const float* emb_B  = (const float*)d_in[5];
    const float* vals_B = (const float*)d_in[6];
    float* out = (float*)d_out;

    // ws layout (bytes):
    char* w = (char*)d_ws;
    int*   cnt    = (int*)w;                                   // 16 B
    int*   list   = (int*)(w + 16);                            // 1 MB
    int*   idxbuf = (int*)(w + 16 + sizeof(int) * (size_t)LCAP);   // 4 MB
    size_t off = 16 + sizeof(int) * (size_t)LCAP + sizeof(int) * (size_t)(2 * NC * NTOK);
    short* xh  = (short*)(w + off); off += (size_t)NTOK * DMODEL * 2;
    short* xl  = (short*)(w + off); off += (size_t)NTOK * DMODEL * 2;
    short* whA = (short*)(w + off); off += (size_t)1024 * DMODEL * 2;
    short* wlA = (short*)(w + off); off += (size_t)1024 * DMODEL * 2;
    short* whB = (short*)(w + off); off += (size_t)1024 * DMODEL * 2;
    short* wlB = (short*)(w + off);

    hipMemsetAsync(cnt, 0, sizeof(int), stream);
    k_split<<<5120, 256, 0, stream>>>(x, W_A, W_B, xh, xl, whA, wlA, whB, wlB);
    k_mfma_argmin<<<dim3(64, 16), 256, 0, stream>>>(xh, xl, whA, wlA, whB, wlB,
                                                    emb_A, emb_B, idxbuf, list, cnt);
    k_refine<<<1024, 256, 0, stream>>>(x, W_A, W_B, emb_A, emb_B, list, cnt, idxbuf);
    k_combine<<<NTOK, 256, 0, stream>>>(x, vals_A, vals_B, idxbuf, out);
}